// Round 1
// baseline (1348.618 us; speedup 1.0000x reference)
//
#include <hip/hip_runtime.h>
#include <hip/hip_bf16.h>

// Problem constants
#define BS_   32
#define LQ_   300
#define LV_   13294
#define EMBED_ 256
#define HEADS_ 8
#define HEAD_DIM_ 32

// ---------------------------------------------------------------------------
// Generic fp32 tiled GEMM: C[M,N] = A[M,K] @ B[K,N] + bias[N]
// BM=BN=64, BK=16, 256 threads, 4x4 acc per thread.
// STORE_MODE 0: f32 row-major C.
// STORE_MODE 1: bf16 store to value_p layout [b, head, pos, 32] where
//               m = b*LV_ + pos, n = head*32 + c.
// All shapes used are exact multiples of tiles -> no guards.
// ---------------------------------------------------------------------------
template <int STORE_MODE>
__global__ __launch_bounds__(256) void gemm_bias(
    const float* __restrict__ A, const float* __restrict__ B,
    const float* __restrict__ bias, void* __restrict__ Cout,
    int M, int N, int K) {
  __shared__ float As[16][64 + 1];   // [k][m], padded
  __shared__ float Bs[16][64];       // [k][n]

  const int tid = threadIdx.x;
  const int tx = tid & 15;          // n-quarter lane
  const int ty = tid >> 4;          // m-quarter lane (0..15)
  const int row0 = blockIdx.x * 64;
  const int col0 = blockIdx.y * 64;

  float acc[4][4];
#pragma unroll
  for (int i = 0; i < 4; ++i)
#pragma unroll
    for (int j = 0; j < 4; ++j) acc[i][j] = 0.f;

  for (int k0 = 0; k0 < K; k0 += 16) {
    // A tile 64x16 -> As[k][m]
    {
      const int r = tid >> 4;   // 0..15
      const int c = tid & 15;   // 0..15 (k within tile)
#pragma unroll
      for (int i = 0; i < 4; ++i) {
        As[c][r + i * 16] = A[(size_t)(row0 + r + i * 16) * K + k0 + c];
      }
    }
    // B tile 16x64 -> Bs[k][n]
    {
      const int r = tid >> 6;   // 0..3
      const int c = tid & 63;   // 0..63
#pragma unroll
      for (int i = 0; i < 4; ++i) {
        Bs[r + i * 4][c] = B[(size_t)(k0 + r + i * 4) * N + col0 + c];
      }
    }
    __syncthreads();

#pragma unroll
    for (int k = 0; k < 16; ++k) {
      float a[4], b[4];
#pragma unroll
      for (int i = 0; i < 4; ++i) a[i] = As[k][ty + i * 16];
#pragma unroll
      for (int j = 0; j < 4; ++j) b[j] = Bs[k][tx + j * 16];
#pragma unroll
      for (int i = 0; i < 4; ++i)
#pragma unroll
        for (int j = 0; j < 4; ++j) acc[i][j] += a[i] * b[j];
    }
    __syncthreads();
  }

#pragma unroll
  for (int i = 0; i < 4; ++i) {
    const int m = row0 + ty + i * 16;
#pragma unroll
    for (int j = 0; j < 4; ++j) {
      const int n = col0 + tx + j * 16;
      const float v = acc[i][j] + bias[n];
      if (STORE_MODE == 0) {
        ((float*)Cout)[(size_t)m * N + n] = v;
      } else {
        const int b_ = m / LV_;
        const int pos = m - b_ * LV_;
        const int h = n >> 5;
        const int c = n & 31;
        ((__hip_bfloat16*)Cout)[((size_t)(b_ * HEADS_ + h) * LV_ + pos) * HEAD_DIM_ + c] =
            __float2bfloat16(v);
      }
    }
  }
}

// ---------------------------------------------------------------------------
// Softmax over 16 contiguous elements per group (group = row*HEADS + h).
// ---------------------------------------------------------------------------
__global__ void softmax16(const float* __restrict__ logits,
                          float* __restrict__ attn, int ngroups) {
  const int g = blockIdx.x * blockDim.x + threadIdx.x;
  if (g >= ngroups) return;
  const float* in = logits + (size_t)g * 16;
  float v[16];
  float m = -1e30f;
#pragma unroll
  for (int i = 0; i < 16; ++i) {
    v[i] = in[i];
    m = fmaxf(m, v[i]);
  }
  float s = 0.f;
#pragma unroll
  for (int i = 0; i < 16; ++i) {
    v[i] = __expf(v[i] - m);
    s += v[i];
  }
  const float inv = 1.0f / s;
  float* out = attn + (size_t)g * 16;
#pragma unroll
  for (int i = 0; i < 16; ++i) out[i] = v[i] * inv;
}

// ---------------------------------------------------------------------------
// Deformable sampling: one thread per (b, q, head, channel).
// value_p layout: [b, head, pos, 32] bf16, level-concatenated pos.
// ---------------------------------------------------------------------------
__global__ __launch_bounds__(256) void msda_sample(
    const float* __restrict__ ref_pts,   // [BS*LQ, 4, 2]
    const float* __restrict__ offsets,   // [BS*LQ, 256]  (h,l,p,2)
    const float* __restrict__ attn,      // [BS*LQ, 128]  (h,l,p)
    const __hip_bfloat16* __restrict__ value_p,
    float* __restrict__ tmp)             // [BS*LQ, 256]
{
  const int t = blockIdx.x * 256 + threadIdx.x;
  const int c = t & 31;
  const int h = (t >> 5) & 7;
  const int row = t >> 8;               // b*LQ + q
  const int b = row / LQ_;

  const int HS[4] = {100, 50, 25, 13};
  const int START[4] = {0, 10000, 12500, 13125};

  const float* offr = offsets + (size_t)row * 256 + h * 32;
  const float* attr = attn + (size_t)row * 128 + h * 16;
  const float* refr = ref_pts + (size_t)row * 8;

  float acc = 0.f;
#pragma unroll
  for (int l = 0; l < 4; ++l) {
    const int HH = HS[l];
    const int WW = HS[l];
    const float fH = (float)HH, fW = (float)WW;
    const float rx = refr[l * 2 + 0];
    const float ry = refr[l * 2 + 1];
    const __hip_bfloat16* vbase =
        value_p + ((size_t)(b * HEADS_ + h) * LV_ + START[l]) * HEAD_DIM_ + c;
#pragma unroll
    for (int p = 0; p < 4; ++p) {
      const float ox = offr[(l * 4 + p) * 2 + 0];
      const float oy = offr[(l * 4 + p) * 2 + 1];
      // loc = ref + off/norm ; x = loc_x*W - 0.5 ; y = loc_y*H - 0.5
      const float x = (rx + ox / fW) * fW - 0.5f;
      const float y = (ry + oy / fH) * fH - 0.5f;
      const float x0f = floorf(x), y0f = floorf(y);
      const float fx = x - x0f, fy = y - y0f;
      const int x0 = (int)x0f, y0 = (int)y0f;
      const float w = attr[l * 4 + p];
      const float w00 = (1.f - fy) * (1.f - fx) * w;
      const float w01 = (1.f - fy) * fx * w;
      const float w10 = fy * (1.f - fx) * w;
      const float w11 = fy * fx * w;
      const bool yin0 = (y0 >= 0) && (y0 < HH);
      const bool yin1 = (y0 + 1 >= 0) && (y0 + 1 < HH);
      const bool xin0 = (x0 >= 0) && (x0 < WW);
      const bool xin1 = (x0 + 1 >= 0) && (x0 + 1 < WW);
      float v00 = 0.f, v01 = 0.f, v10 = 0.f, v11 = 0.f;
      if (yin0 && xin0) v00 = __bfloat162float(vbase[((size_t)y0 * WW + x0) * HEAD_DIM_]);
      if (yin0 && xin1) v01 = __bfloat162float(vbase[((size_t)y0 * WW + x0 + 1) * HEAD_DIM_]);
      if (yin1 && xin0) v10 = __bfloat162float(vbase[((size_t)(y0 + 1) * WW + x0) * HEAD_DIM_]);
      if (yin1 && xin1) v11 = __bfloat162float(vbase[((size_t)(y0 + 1) * WW + x0 + 1) * HEAD_DIM_]);
      acc += w00 * v00 + w01 * v01 + w10 * v10 + w11 * v11;
    }
  }
  tmp[(size_t)row * 256 + h * 32 + c] = acc;
}

// ---------------------------------------------------------------------------
extern "C" void kernel_launch(void* const* d_in, const int* in_sizes, int n_in,
                              void* d_out, int out_size, void* d_ws, size_t ws_size,
                              hipStream_t stream) {
  const float* query  = (const float*)d_in[0];   // [32,300,256]
  const float* refpts = (const float*)d_in[1];   // [32,300,4,2]
  const float* value  = (const float*)d_in[2];   // [32,13294,256]
  // d_in[3] = value_spatial_shapes (int64) -- hardcoded
  const float* W_off  = (const float*)d_in[4];
  const float* b_off  = (const float*)d_in[5];
  const float* W_attn = (const float*)d_in[6];
  const float* b_attn = (const float*)d_in[7];
  const float* W_val  = (const float*)d_in[8];
  const float* b_val  = (const float*)d_in[9];
  const float* W_out  = (const float*)d_in[10];
  const float* b_out  = (const float*)d_in[11];
  float* out = (float*)d_out;

  char* ws = (char*)d_ws;
  __hip_bfloat16* value_p = (__hip_bfloat16*)ws;              // 32*8*13294*32*2 = 217,710,592 B
  size_t off = (size_t)BS_ * HEADS_ * LV_ * HEAD_DIM_ * 2;
  float* offsets = (float*)(ws + off); off += (size_t)BS_ * LQ_ * 256 * 4;   // 9,830,400
  float* logits  = (float*)(ws + off); off += (size_t)BS_ * LQ_ * 128 * 4;   // 4,915,200
  float* attn    = (float*)(ws + off); off += (size_t)BS_ * LQ_ * 128 * 4;   // 4,915,200
  float* tmp     = (float*)(ws + off); off += (size_t)BS_ * LQ_ * 256 * 4;   // 9,830,400

  const int M1 = BS_ * LV_;   // 425408 = 64*6647
  const int MQ = BS_ * LQ_;   // 9600   = 64*150

  // value projection -> bf16 [b,h,pos,32]
  gemm_bias<1><<<dim3(M1 / 64, 256 / 64), 256, 0, stream>>>(value, W_val, b_val, value_p, M1, 256, 256);
  // offsets projection
  gemm_bias<0><<<dim3(MQ / 64, 256 / 64), 256, 0, stream>>>(query, W_off, b_off, offsets, MQ, 256, 256);
  // attention logits
  gemm_bias<0><<<dim3(MQ / 64, 128 / 64), 256, 0, stream>>>(query, W_attn, b_attn, logits, MQ, 128, 256);
  // softmax over 16 per (row, head)
  softmax16<<<(MQ * HEADS_ + 255) / 256, 256, 0, stream>>>(logits, attn, MQ * HEADS_);
  // deformable bilinear sampling + weighted sum
  msda_sample<<<(MQ * 256) / 256, 256, 0, stream>>>(refpts, offsets, attn, value_p, tmp);
  // output projection
  gemm_bias<0><<<dim3(MQ / 64, 256 / 64), 256, 0, stream>>>(tmp, W_out, b_out, out, MQ, 256, 256);
}

// Round 2
// 643.897 us; speedup vs baseline: 2.0945x; 2.0945x over previous
//
#include <hip/hip_runtime.h>
#include <hip/hip_bf16.h>

// Problem constants
#define BS_   32
#define LQ_   300
#define LV_   13294
#define EMBED_ 256
#define HEADS_ 8
#define HEAD_DIM_ 32

typedef __attribute__((ext_vector_type(8))) short bf16x8;
typedef __attribute__((ext_vector_type(4))) float f32x4;

__device__ inline short f2bf(float f) {   // RNE fp32->bf16 (bit trick)
  union { float f; unsigned u; } x; x.f = f;
  return (short)((x.u + 0x7FFF + ((x.u >> 16) & 1)) >> 16);
}

// ---------------------------------------------------------------------------
// W_val [256 k][256 n] fp32 -> Wt [256 n][256 k] bf16
// ---------------------------------------------------------------------------
__global__ void convert_wt(const float* __restrict__ W, short* __restrict__ Wt) {
  const int n = blockIdx.x;
  const int k = threadIdx.x;
  Wt[n * 256 + k] = f2bf(W[k * 256 + n]);
}

// ---------------------------------------------------------------------------
// Value projection via bf16 MFMA: Vp = bf16(value @ W_val + b_val)
// A [M,256] fp32, Wt [256 n][256 k] bf16. Output layout [b][h][pos][32] bf16.
// BM=64, BN=128, BK=32, 256 threads (4 waves as 2x2), mfma_f32_16x16x32_bf16.
// M = 425408 = 64*6647 exactly; N=256 -> 2 col blocks. No guards needed.
// ---------------------------------------------------------------------------
__global__ __launch_bounds__(256) void gemm_value_mfma(
    const float* __restrict__ A, const short* __restrict__ Wt,
    const float* __restrict__ bias, short* __restrict__ Vp) {
  __shared__ short As[64 * 40];    // [row][k] padded to 40 shorts (80 B)
  __shared__ short Bs[128 * 40];   // [n][k] padded

  const int tid = threadIdx.x;
  const int lane = tid & 63;
  const int w = tid >> 6;
  const int wm = w >> 1, wn = w & 1;          // 2x2 wave grid
  const size_t m0 = (size_t)blockIdx.x * 64;
  const int col0 = blockIdx.y * 128;

  // A staging: float4 groups. g = tid + i*256 (i=0,1); row=g/8, kq=g%8.
  const int ar0 = tid >> 3, akq0 = tid & 7;          // i=0
  const int ar1 = (tid + 256) >> 3, akq1 = tid & 7;  // i=1 (row+32, same kq)
  // B staging: bf16x8 groups. g = tid + i*256; row=g/4, ko=(g%4)*8.
  const int br0 = tid >> 2, bko0 = (tid & 3) * 8;
  const int br1 = (tid + 256) >> 2, bko1 = (tid & 3) * 8;

  const float* aP0 = A + (m0 + ar0) * 256 + akq0 * 4;
  const float* aP1 = A + (m0 + ar1) * 256 + akq1 * 4;
  const short* bP0 = Wt + (size_t)(col0 + br0) * 256 + bko0;
  const short* bP1 = Wt + (size_t)(col0 + br1) * 256 + bko1;

  f32x4 acc[2][4];
#pragma unroll
  for (int i = 0; i < 2; ++i)
#pragma unroll
    for (int j = 0; j < 4; ++j) acc[i][j] = (f32x4){0.f, 0.f, 0.f, 0.f};

  f32x4 ra0, ra1;
  bf16x8 rb0, rb1;
  // prefetch k-tile 0
  ra0 = *(const f32x4*)(aP0);
  ra1 = *(const f32x4*)(aP1);
  rb0 = *(const bf16x8*)(bP0);
  rb1 = *(const bf16x8*)(bP1);

  const int aw0 = ar0 * 40 + akq0 * 4;
  const int aw1 = ar1 * 40 + akq1 * 4;
  const int bw0 = br0 * 40 + bko0;
  const int bw1 = br1 * 40 + bko1;
  const int a_rd = (wm * 32 + (lane & 15)) * 40 + (lane >> 4) * 8;
  const int b_rd = (wn * 64 + (lane & 15)) * 40 + (lane >> 4) * 8;

  typedef __attribute__((ext_vector_type(4))) short s16x4;
  for (int kt = 0; kt < 8; ++kt) {
    // stage regs -> LDS (convert A to bf16)
    s16x4 ca0, ca1;
#pragma unroll
    for (int i = 0; i < 4; ++i) { ca0[i] = f2bf(ra0[i]); ca1[i] = f2bf(ra1[i]); }
    *(s16x4*)(As + aw0) = ca0;
    *(s16x4*)(As + aw1) = ca1;
    *(bf16x8*)(Bs + bw0) = rb0;
    *(bf16x8*)(Bs + bw1) = rb1;
    __syncthreads();
    if (kt < 7) {  // issue next tile's global loads; overlap with ds_read+MFMA
      const int k0 = (kt + 1) * 32;
      ra0 = *(const f32x4*)(aP0 + k0);
      ra1 = *(const f32x4*)(aP1 + k0);
      rb0 = *(const bf16x8*)(bP0 + k0);
      rb1 = *(const bf16x8*)(bP1 + k0);
    }
    bf16x8 af[2], bfr[4];
#pragma unroll
    for (int mf = 0; mf < 2; ++mf) af[mf] = *(const bf16x8*)(As + a_rd + mf * 16 * 40);
#pragma unroll
    for (int nf = 0; nf < 4; ++nf) bfr[nf] = *(const bf16x8*)(Bs + b_rd + nf * 16 * 40);
#pragma unroll
    for (int mf = 0; mf < 2; ++mf)
#pragma unroll
      for (int nf = 0; nf < 4; ++nf)
        acc[mf][nf] = __builtin_amdgcn_mfma_f32_16x16x32_bf16(af[mf], bfr[nf], acc[mf][nf], 0, 0, 0);
    __syncthreads();
  }

  // epilogue: D lane map col=lane&15, row=4*(lane>>4)+reg (m89)
  float bv[4];
#pragma unroll
  for (int nf = 0; nf < 4; ++nf) bv[nf] = bias[col0 + wn * 64 + nf * 16 + (lane & 15)];
#pragma unroll
  for (int mf = 0; mf < 2; ++mf) {
#pragma unroll
    for (int r = 0; r < 4; ++r) {
      const unsigned m = (unsigned)(m0 + wm * 32 + mf * 16 + (lane >> 4) * 4 + r);
      const unsigned b_ = m / LV_;
      const unsigned pos = m - b_ * LV_;
#pragma unroll
      for (int nf = 0; nf < 4; ++nf) {
        const int n = col0 + wn * 64 + nf * 16 + (lane & 15);
        const int h = n >> 5, c = n & 31;
        Vp[((size_t)(b_ * HEADS_ + h) * LV_ + pos) * HEAD_DIM_ + c] =
            f2bf(acc[mf][nf][r] + bv[nf]);
      }
    }
  }
}

// ---------------------------------------------------------------------------
// Generic fp32 tiled GEMM (for the small query-side projections).
// ---------------------------------------------------------------------------
__global__ __launch_bounds__(256) void gemm_bias(
    const float* __restrict__ A, const float* __restrict__ B,
    const float* __restrict__ bias, float* __restrict__ C,
    int M, int N, int K) {
  __shared__ float As[16][64 + 1];
  __shared__ float Bs[16][64];

  const int tid = threadIdx.x;
  const int tx = tid & 15;
  const int ty = tid >> 4;
  const int row0 = blockIdx.x * 64;
  const int col0 = blockIdx.y * 64;

  float acc[4][4];
#pragma unroll
  for (int i = 0; i < 4; ++i)
#pragma unroll
    for (int j = 0; j < 4; ++j) acc[i][j] = 0.f;

  for (int k0 = 0; k0 < K; k0 += 16) {
    {
      const int r = tid >> 4;
      const int c = tid & 15;
#pragma unroll
      for (int i = 0; i < 4; ++i)
        As[c][r + i * 16] = A[(size_t)(row0 + r + i * 16) * K + k0 + c];
    }
    {
      const int r = tid >> 6;
      const int c = tid & 63;
#pragma unroll
      for (int i = 0; i < 4; ++i)
        Bs[r + i * 4][c] = B[(size_t)(k0 + r + i * 4) * N + col0 + c];
    }
    __syncthreads();
#pragma unroll
    for (int k = 0; k < 16; ++k) {
      float a[4], b[4];
#pragma unroll
      for (int i = 0; i < 4; ++i) a[i] = As[k][ty + i * 16];
#pragma unroll
      for (int j = 0; j < 4; ++j) b[j] = Bs[k][tx + j * 16];
#pragma unroll
      for (int i = 0; i < 4; ++i)
#pragma unroll
        for (int j = 0; j < 4; ++j) acc[i][j] += a[i] * b[j];
    }
    __syncthreads();
  }

#pragma unroll
  for (int i = 0; i < 4; ++i) {
    const int m = row0 + ty + i * 16;
#pragma unroll
    for (int j = 0; j < 4; ++j) {
      const int n = col0 + tx + j * 16;
      C[(size_t)m * N + n] = acc[i][j] + bias[n];
    }
  }
}

// ---------------------------------------------------------------------------
__global__ void softmax16(const float* __restrict__ logits,
                          float* __restrict__ attn, int ngroups) {
  const int g = blockIdx.x * blockDim.x + threadIdx.x;
  if (g >= ngroups) return;
  const float* in = logits + (size_t)g * 16;
  float v[16];
  float m = -1e30f;
#pragma unroll
  for (int i = 0; i < 16; ++i) { v[i] = in[i]; m = fmaxf(m, v[i]); }
  float s = 0.f;
#pragma unroll
  for (int i = 0; i < 16; ++i) { v[i] = __expf(v[i] - m); s += v[i]; }
  const float inv = 1.0f / s;
  float* out = attn + (size_t)g * 16;
#pragma unroll
  for (int i = 0; i < 16; ++i) out[i] = v[i] * inv;
}

// ---------------------------------------------------------------------------
// Deformable sampling: one thread per (b, q, head, channel).
// ---------------------------------------------------------------------------
__global__ __launch_bounds__(256) void msda_sample(
    const float* __restrict__ ref_pts,
    const float* __restrict__ offsets,
    const float* __restrict__ attn,
    const __hip_bfloat16* __restrict__ value_p,
    float* __restrict__ tmp) {
  const int t = blockIdx.x * 256 + threadIdx.x;
  const int c = t & 31;
  const int h = (t >> 5) & 7;
  const int row = t >> 8;
  const int b = row / LQ_;

  const int HS[4] = {100, 50, 25, 13};
  const int START[4] = {0, 10000, 12500, 13125};

  const float* offr = offsets + (size_t)row * 256 + h * 32;
  const float* attr = attn + (size_t)row * 128 + h * 16;
  const float* refr = ref_pts + (size_t)row * 8;

  float acc = 0.f;
#pragma unroll
  for (int l = 0; l < 4; ++l) {
    const int HH = HS[l];
    const int WW = HS[l];
    const float fH = (float)HH, fW = (float)WW;
    const float rx = refr[l * 2 + 0];
    const float ry = refr[l * 2 + 1];
    const __hip_bfloat16* vbase =
        value_p + ((size_t)(b * HEADS_ + h) * LV_ + START[l]) * HEAD_DIM_ + c;
#pragma unroll
    for (int p = 0; p < 4; ++p) {
      const float ox = offr[(l * 4 + p) * 2 + 0];
      const float oy = offr[(l * 4 + p) * 2 + 1];
      const float x = (rx + ox / fW) * fW - 0.5f;
      const float y = (ry + oy / fH) * fH - 0.5f;
      const float x0f = floorf(x), y0f = floorf(y);
      const float fx = x - x0f, fy = y - y0f;
      const int x0 = (int)x0f, y0 = (int)y0f;
      const float wgt = attr[l * 4 + p];
      const float w00 = (1.f - fy) * (1.f - fx) * wgt;
      const float w01 = (1.f - fy) * fx * wgt;
      const float w10 = fy * (1.f - fx) * wgt;
      const float w11 = fy * fx * wgt;
      const bool yin0 = (y0 >= 0) && (y0 < HH);
      const bool yin1 = (y0 + 1 >= 0) && (y0 + 1 < HH);
      const bool xin0 = (x0 >= 0) && (x0 < WW);
      const bool xin1 = (x0 + 1 >= 0) && (x0 + 1 < WW);
      float v00 = 0.f, v01 = 0.f, v10 = 0.f, v11 = 0.f;
      if (yin0 && xin0) v00 = __bfloat162float(vbase[((size_t)y0 * WW + x0) * HEAD_DIM_]);
      if (yin0 && xin1) v01 = __bfloat162float(vbase[((size_t)y0 * WW + x0 + 1) * HEAD_DIM_]);
      if (yin1 && xin0) v10 = __bfloat162float(vbase[((size_t)(y0 + 1) * WW + x0) * HEAD_DIM_]);
      if (yin1 && xin1) v11 = __bfloat162float(vbase[((size_t)(y0 + 1) * WW + x0 + 1) * HEAD_DIM_]);
      acc += w00 * v00 + w01 * v01 + w10 * v10 + w11 * v11;
    }
  }
  tmp[(size_t)row * 256 + h * 32 + c] = acc;
}

// ---------------------------------------------------------------------------
extern "C" void kernel_launch(void* const* d_in, const int* in_sizes, int n_in,
                              void* d_out, int out_size, void* d_ws, size_t ws_size,
                              hipStream_t stream) {
  const float* query  = (const float*)d_in[0];
  const float* refpts = (const float*)d_in[1];
  const float* value  = (const float*)d_in[2];
  const float* W_off  = (const float*)d_in[4];
  const float* b_off  = (const float*)d_in[5];
  const float* W_attn = (const float*)d_in[6];
  const float* b_attn = (const float*)d_in[7];
  const float* W_val  = (const float*)d_in[8];
  const float* b_val  = (const float*)d_in[9];
  const float* W_out  = (const float*)d_in[10];
  const float* b_out  = (const float*)d_in[11];
  float* out = (float*)d_out;

  char* ws = (char*)d_ws;
  short* value_p = (short*)ws;                                 // 217,710,592 B
  size_t off = (size_t)BS_ * HEADS_ * LV_ * HEAD_DIM_ * 2;
  float* offsets = (float*)(ws + off); off += (size_t)BS_ * LQ_ * 256 * 4;
  float* logits  = (float*)(ws + off); off += (size_t)BS_ * LQ_ * 128 * 4;
  float* attn    = (float*)(ws + off); off += (size_t)BS_ * LQ_ * 128 * 4;
  float* tmp     = (float*)(ws + off); off += (size_t)BS_ * LQ_ * 256 * 4;
  // Wt (131072 B) aliases tmp: Wt is consumed by gemm_value_mfma before
  // msda_sample writes tmp. Same-stream ordering guarantees safety.
  short* Wt = (short*)tmp;

  const int M1 = BS_ * LV_;   // 425408 = 64*6647
  const int MQ = BS_ * LQ_;   // 9600

  convert_wt<<<256, 256, 0, stream>>>(W_val, Wt);
  gemm_value_mfma<<<dim3(M1 / 64, 2), 256, 0, stream>>>(value, Wt, b_val, value_p);
  gemm_bias<<<dim3(MQ / 64, 256 / 64), 256, 0, stream>>>(query, W_off, b_off, offsets, MQ, 256, 256);
  gemm_bias<<<dim3(MQ / 64, 128 / 64), 256, 0, stream>>>(query, W_attn, b_attn, logits, MQ, 128, 256);
  softmax16<<<(MQ * HEADS_ + 255) / 256, 256, 0, stream>>>(logits, attn, MQ * HEADS_);
  msda_sample<<<(MQ * 256) / 256, 256, 0, stream>>>(refpts, offsets, attn,
                                                    (const __hip_bfloat16*)value_p, tmp);
  gemm_bias<<<dim3(MQ / 64, 256 / 64), 256, 0, stream>>>(tmp, W_out, b_out, out, MQ, 256, 256);
}

// Round 3
// 585.147 us; speedup vs baseline: 2.3048x; 1.1004x over previous
//
#include <hip/hip_runtime.h>
#include <hip/hip_bf16.h>

// Problem constants
#define BS_   32
#define LQ_   300
#define LV_   13294
#define EMBED_ 256
#define HEADS_ 8
#define HEAD_DIM_ 32

typedef __attribute__((ext_vector_type(8))) short bf16x8;
typedef __attribute__((ext_vector_type(4))) float f32x4;

__device__ inline short f2bf(float f) {   // RNE fp32->bf16 (bit trick)
  union { float f; unsigned u; } x; x.f = f;
  return (short)((x.u + 0x7FFF + ((x.u >> 16) & 1)) >> 16);
}
__device__ inline float bf2f(short s) {
  union { unsigned u; float f; } x; x.u = ((unsigned)(unsigned short)s) << 16;
  return x.f;
}

// ---------------------------------------------------------------------------
// W_val [256 k][256 n] fp32 -> Wt [256 n][256 k] bf16
// ---------------------------------------------------------------------------
__global__ void convert_wt(const float* __restrict__ W, short* __restrict__ Wt) {
  const int n = blockIdx.x;
  const int k = threadIdx.x;
  Wt[n * 256 + k] = f2bf(W[k * 256 + n]);
}

// ---------------------------------------------------------------------------
// Value projection, LDS-free MFMA GEMM.
// Vp = bf16(value @ W_val + b_val), output layout [b][h][pos][32].
// BM=32 (425408 = 32*13294 blocks), BN=256 via 4 waves x 64 cols.
// Per wave, per k-step(32): A frags direct global->reg (fp32, cvt to bf16),
// B frags direct global->reg (bf16, L2-resident 128KB). Register
// double-buffer one k-step ahead; fully unrolled (static indices).
// A fragment (16x16x32): lane holds row=lane&15, k=(lane>>4)*8 .. +7.
// B fragment: col=lane&15, same k group. D: col=lane&15, row=(lane>>4)*4+r.
// ---------------------------------------------------------------------------
__global__ __launch_bounds__(256) void gemm_value_mfma(
    const float* __restrict__ A, const short* __restrict__ Wt,
    const float* __restrict__ bias, short* __restrict__ Vp) {
  const int tid = threadIdx.x;
  const int lane = tid & 63;
  const int wn = tid >> 6;                 // wave's n-quarter (0..3)
  const size_t m0 = (size_t)blockIdx.x * 32;
  const int n0 = wn * 64;
  const int lr = lane & 15;                // fragment row/col lane
  const int lk = (lane >> 4) * 8;          // k-group offset

  const float* ap0 = A + (m0 + lr) * 256 + lk;        // mf=0
  const float* ap1 = A + (m0 + 16 + lr) * 256 + lk;   // mf=1
  const short* bp0 = Wt + (size_t)(n0 +  0 + lr) * 256 + lk;
  const short* bp1 = Wt + (size_t)(n0 + 16 + lr) * 256 + lk;
  const short* bp2 = Wt + (size_t)(n0 + 32 + lr) * 256 + lk;
  const short* bp3 = Wt + (size_t)(n0 + 48 + lr) * 256 + lk;

  f32x4 acc[2][4];
#pragma unroll
  for (int i = 0; i < 2; ++i)
#pragma unroll
    for (int j = 0; j < 4; ++j) acc[i][j] = (f32x4){0.f, 0.f, 0.f, 0.f};

  // register double-buffer (indices become constants after full unroll)
  f32x4 ra0[2], ra0h[2], ra1[2], ra1h[2];
  bf16x8 rb0[2], rb1[2], rb2[2], rb3[2];

  ra0[0]  = *(const f32x4*)(ap0);
  ra0h[0] = *(const f32x4*)(ap0 + 4);
  ra1[0]  = *(const f32x4*)(ap1);
  ra1h[0] = *(const f32x4*)(ap1 + 4);
  rb0[0] = *(const bf16x8*)(bp0);
  rb1[0] = *(const bf16x8*)(bp1);
  rb2[0] = *(const bf16x8*)(bp2);
  rb3[0] = *(const bf16x8*)(bp3);

#pragma unroll
  for (int kt = 0; kt < 8; ++kt) {
    const int cur = kt & 1;
    const int nxt = cur ^ 1;
    if (kt < 7) {
      const int k0 = (kt + 1) * 32;
      ra0[nxt]  = *(const f32x4*)(ap0 + k0);
      ra0h[nxt] = *(const f32x4*)(ap0 + k0 + 4);
      ra1[nxt]  = *(const f32x4*)(ap1 + k0);
      ra1h[nxt] = *(const f32x4*)(ap1 + k0 + 4);
      rb0[nxt] = *(const bf16x8*)(bp0 + k0);
      rb1[nxt] = *(const bf16x8*)(bp1 + k0);
      rb2[nxt] = *(const bf16x8*)(bp2 + k0);
      rb3[nxt] = *(const bf16x8*)(bp3 + k0);
    }
    bf16x8 af0, af1;
#pragma unroll
    for (int i = 0; i < 4; ++i) {
      af0[i]     = f2bf(ra0[cur][i]);
      af0[i + 4] = f2bf(ra0h[cur][i]);
      af1[i]     = f2bf(ra1[cur][i]);
      af1[i + 4] = f2bf(ra1h[cur][i]);
    }
    acc[0][0] = __builtin_amdgcn_mfma_f32_16x16x32_bf16(af0, rb0[cur], acc[0][0], 0, 0, 0);
    acc[0][1] = __builtin_amdgcn_mfma_f32_16x16x32_bf16(af0, rb1[cur], acc[0][1], 0, 0, 0);
    acc[0][2] = __builtin_amdgcn_mfma_f32_16x16x32_bf16(af0, rb2[cur], acc[0][2], 0, 0, 0);
    acc[0][3] = __builtin_amdgcn_mfma_f32_16x16x32_bf16(af0, rb3[cur], acc[0][3], 0, 0, 0);
    acc[1][0] = __builtin_amdgcn_mfma_f32_16x16x32_bf16(af1, rb0[cur], acc[1][0], 0, 0, 0);
    acc[1][1] = __builtin_amdgcn_mfma_f32_16x16x32_bf16(af1, rb1[cur], acc[1][1], 0, 0, 0);
    acc[1][2] = __builtin_amdgcn_mfma_f32_16x16x32_bf16(af1, rb2[cur], acc[1][2], 0, 0, 0);
    acc[1][3] = __builtin_amdgcn_mfma_f32_16x16x32_bf16(af1, rb3[cur], acc[1][3], 0, 0, 0);
  }

  // epilogue: D map col=lane&15, row=(lane>>4)*4+r
  float bv[4];
#pragma unroll
  for (int nf = 0; nf < 4; ++nf) bv[nf] = bias[n0 + nf * 16 + lr];
  const int lq4 = (lane >> 4) * 4;
#pragma unroll
  for (int mf = 0; mf < 2; ++mf) {
#pragma unroll
    for (int r = 0; r < 4; ++r) {
      const unsigned m = (unsigned)m0 + mf * 16 + lq4 + r;
      const unsigned b_ = m / LV_;
      const unsigned pos = m - b_ * LV_;
#pragma unroll
      for (int nf = 0; nf < 4; ++nf) {
        const int n = n0 + nf * 16 + lr;
        const int h = n >> 5, c = n & 31;
        Vp[((size_t)(b_ * HEADS_ + h) * LV_ + pos) * HEAD_DIM_ + c] =
            f2bf(acc[mf][nf][r] + bv[nf]);
      }
    }
  }
}

// ---------------------------------------------------------------------------
// Generic fp32 tiled GEMM (small query-side projections).
// ---------------------------------------------------------------------------
__global__ __launch_bounds__(256) void gemm_bias(
    const float* __restrict__ A, const float* __restrict__ B,
    const float* __restrict__ bias, float* __restrict__ C,
    int M, int N, int K) {
  __shared__ float As[16][64 + 1];
  __shared__ float Bs[16][64];

  const int tid = threadIdx.x;
  const int tx = tid & 15;
  const int ty = tid >> 4;
  const int row0 = blockIdx.x * 64;
  const int col0 = blockIdx.y * 64;

  float acc[4][4];
#pragma unroll
  for (int i = 0; i < 4; ++i)
#pragma unroll
    for (int j = 0; j < 4; ++j) acc[i][j] = 0.f;

  for (int k0 = 0; k0 < K; k0 += 16) {
    {
      const int r = tid >> 4;
      const int c = tid & 15;
#pragma unroll
      for (int i = 0; i < 4; ++i)
        As[c][r + i * 16] = A[(size_t)(row0 + r + i * 16) * K + k0 + c];
    }
    {
      const int r = tid >> 6;
      const int c = tid & 63;
#pragma unroll
      for (int i = 0; i < 4; ++i)
        Bs[r + i * 4][c] = B[(size_t)(k0 + r + i * 4) * N + col0 + c];
    }
    __syncthreads();
#pragma unroll
    for (int k = 0; k < 16; ++k) {
      float a[4], b[4];
#pragma unroll
      for (int i = 0; i < 4; ++i) a[i] = As[k][ty + i * 16];
#pragma unroll
      for (int j = 0; j < 4; ++j) b[j] = Bs[k][tx + j * 16];
#pragma unroll
      for (int i = 0; i < 4; ++i)
#pragma unroll
        for (int j = 0; j < 4; ++j) acc[i][j] += a[i] * b[j];
    }
    __syncthreads();
  }

#pragma unroll
  for (int i = 0; i < 4; ++i) {
    const int m = row0 + ty + i * 16;
#pragma unroll
    for (int j = 0; j < 4; ++j) {
      const int n = col0 + tx + j * 16;
      C[(size_t)m * N + n] = acc[i][j] + bias[n];
    }
  }
}

// ---------------------------------------------------------------------------
__global__ void softmax16(const float* __restrict__ logits,
                          float* __restrict__ attn, int ngroups) {
  const int g = blockIdx.x * blockDim.x + threadIdx.x;
  if (g >= ngroups) return;
  const float* in = logits + (size_t)g * 16;
  float v[16];
  float m = -1e30f;
#pragma unroll
  for (int i = 0; i < 16; ++i) { v[i] = in[i]; m = fmaxf(m, v[i]); }
  float s = 0.f;
#pragma unroll
  for (int i = 0; i < 16; ++i) { v[i] = __expf(v[i] - m); s += v[i]; }
  const float inv = 1.0f / s;
  float* out = attn + (size_t)g * 16;
#pragma unroll
  for (int i = 0; i < 16; ++i) out[i] = v[i] * inv;
}

// ---------------------------------------------------------------------------
// Deformable sampling: one thread per (b, q, head, 8-channel group).
// bf16x8 (16B) gathers, branchless clamp+mask bilinear.
// ---------------------------------------------------------------------------
__global__ __launch_bounds__(256) void msda_sample(
    const float* __restrict__ ref_pts,   // [BS*LQ, 4, 2]
    const float* __restrict__ offsets,   // [BS*LQ, 256]  (h,l,p,2)
    const float* __restrict__ attn,      // [BS*LQ, 128]  (h,l,p)
    const short* __restrict__ value_p,   // [b,h,pos,32] bf16
    float* __restrict__ tmp)             // [BS*LQ, 256]
{
  const int t = blockIdx.x * 256 + threadIdx.x;
  const int c8 = t & 3;                 // channel octet: c = c8*8
  const int h = (t >> 2) & 7;
  const int row = t >> 5;               // b*LQ + q
  const int b = row / LQ_;

  const int HS[4] = {100, 50, 25, 13};
  const int START[4] = {0, 10000, 12500, 13125};

  const float* offr = offsets + (size_t)row * 256 + h * 32;
  const float* attr = attn + (size_t)row * 128 + h * 16;
  const float* refr = ref_pts + (size_t)row * 8;

  float acc[8];
#pragma unroll
  for (int j = 0; j < 8; ++j) acc[j] = 0.f;

#pragma unroll
  for (int l = 0; l < 4; ++l) {
    const int HH = HS[l];
    const int WW = HS[l];
    const float fH = (float)HH, fW = (float)WW;
    const float rx = refr[l * 2 + 0];
    const float ry = refr[l * 2 + 1];
    const short* vbase =
        value_p + ((size_t)(b * HEADS_ + h) * LV_ + START[l]) * HEAD_DIM_ + c8 * 8;
#pragma unroll
    for (int p = 0; p < 4; ++p) {
      const float ox = offr[(l * 4 + p) * 2 + 0];
      const float oy = offr[(l * 4 + p) * 2 + 1];
      const float x = (rx + ox / fW) * fW - 0.5f;
      const float y = (ry + oy / fH) * fH - 0.5f;
      const float x0f = floorf(x), y0f = floorf(y);
      const float fx = x - x0f, fy = y - y0f;
      const int x0 = (int)x0f, y0 = (int)y0f;
      const float wgt = attr[l * 4 + p];
      // validity masks as floats (branchless)
      const float iy0 = (y0 >= 0 && y0 < HH) ? 1.f : 0.f;
      const float iy1 = (y0 + 1 >= 0 && y0 + 1 < HH) ? 1.f : 0.f;
      const float ix0 = (x0 >= 0 && x0 < WW) ? 1.f : 0.f;
      const float ix1 = (x0 + 1 >= 0 && x0 + 1 < WW) ? 1.f : 0.f;
      const float w00 = (1.f - fy) * (1.f - fx) * wgt * iy0 * ix0;
      const float w01 = (1.f - fy) * fx * wgt * iy0 * ix1;
      const float w10 = fy * (1.f - fx) * wgt * iy1 * ix0;
      const float w11 = fy * fx * wgt * iy1 * ix1;
      // clamped indices (always-safe addresses)
      const int xc0 = min(max(x0, 0), WW - 1);
      const int xc1 = min(max(x0 + 1, 0), WW - 1);
      const int yc0 = min(max(y0, 0), HH - 1);
      const int yc1 = min(max(y0 + 1, 0), HH - 1);
      const bf16x8 q00 = *(const bf16x8*)(vbase + (size_t)(yc0 * WW + xc0) * HEAD_DIM_);
      const bf16x8 q01 = *(const bf16x8*)(vbase + (size_t)(yc0 * WW + xc1) * HEAD_DIM_);
      const bf16x8 q10 = *(const bf16x8*)(vbase + (size_t)(yc1 * WW + xc0) * HEAD_DIM_);
      const bf16x8 q11 = *(const bf16x8*)(vbase + (size_t)(yc1 * WW + xc1) * HEAD_DIM_);
#pragma unroll
      for (int j = 0; j < 8; ++j) {
        acc[j] += w00 * bf2f(q00[j]) + w01 * bf2f(q01[j]) +
                  w10 * bf2f(q10[j]) + w11 * bf2f(q11[j]);
      }
    }
  }
  float* o = tmp + (size_t)row * 256 + h * 32 + c8 * 8;
  f32x4 o0 = {acc[0], acc[1], acc[2], acc[3]};
  f32x4 o1 = {acc[4], acc[5], acc[6], acc[7]};
  *(f32x4*)(o) = o0;
  *(f32x4*)(o + 4) = o1;
}

// ---------------------------------------------------------------------------
extern "C" void kernel_launch(void* const* d_in, const int* in_sizes, int n_in,
                              void* d_out, int out_size, void* d_ws, size_t ws_size,
                              hipStream_t stream) {
  const float* query  = (const float*)d_in[0];
  const float* refpts = (const float*)d_in[1];
  const float* value  = (const float*)d_in[2];
  const float* W_off  = (const float*)d_in[4];
  const float* b_off  = (const float*)d_in[5];
  const float* W_attn = (const float*)d_in[6];
  const float* b_attn = (const float*)d_in[7];
  const float* W_val  = (const float*)d_in[8];
  const float* b_val  = (const float*)d_in[9];
  const float* W_out  = (const float*)d_in[10];
  const float* b_out  = (const float*)d_in[11];
  float* out = (float*)d_out;

  char* ws = (char*)d_ws;
  short* value_p = (short*)ws;                                 // 217,710,592 B
  size_t off = (size_t)BS_ * HEADS_ * LV_ * HEAD_DIM_ * 2;
  float* offsets = (float*)(ws + off); off += (size_t)BS_ * LQ_ * 256 * 4;
  float* logits  = (float*)(ws + off); off += (size_t)BS_ * LQ_ * 128 * 4;
  float* attn    = (float*)(ws + off); off += (size_t)BS_ * LQ_ * 128 * 4;
  float* tmp     = (float*)(ws + off); off += (size_t)BS_ * LQ_ * 256 * 4;
  // Wt (131072 B) aliases tmp: consumed by gemm_value_mfma before msda writes tmp.
  short* Wt = (short*)tmp;

  const int M1 = BS_ * LV_;   // 425408 = 32*13294
  const int MQ = BS_ * LQ_;   // 9600

  convert_wt<<<256, 256, 0, stream>>>(W_val, Wt);
  gemm_value_mfma<<<M1 / 32, 256, 0, stream>>>(value, Wt, b_val, value_p);
  gemm_bias<<<dim3(MQ / 64, 256 / 64), 256, 0, stream>>>(query, W_off, b_off, offsets, MQ, 256, 256);
  gemm_bias<<<dim3(MQ / 64, 128 / 64), 256, 0, stream>>>(query, W_attn, b_attn, logits, MQ, 128, 256);
  softmax16<<<(MQ * HEADS_ + 255) / 256, 256, 0, stream>>>(logits, attn, MQ * HEADS_);
  msda_sample<<<(MQ * 32) / 256, 256, 0, stream>>>(refpts, offsets, attn, value_p, tmp);
  gemm_bias<<<dim3(MQ / 64, 256 / 64), 256, 0, stream>>>(tmp, W_out, b_out, out, MQ, 256, 256);
}

// Round 4
// 400.361 us; speedup vs baseline: 3.3685x; 1.4615x over previous
//
#include <hip/hip_runtime.h>
#include <hip/hip_bf16.h>

// Problem constants
#define BS_   32
#define LQ_   300
#define LV_   13294
#define EMBED_ 256
#define HEADS_ 8
#define HEAD_DIM_ 32

typedef __attribute__((ext_vector_type(8))) short bf16x8;
typedef __attribute__((ext_vector_type(4))) float f32x4;

__device__ inline short f2bf(float f) {   // RNE fp32->bf16 (bit trick)
  union { float f; unsigned u; } x; x.f = f;
  return (short)((x.u + 0x7FFF + ((x.u >> 16) & 1)) >> 16);
}
__device__ inline float bf2f(short s) {
  union { unsigned u; float f; } x; x.u = ((unsigned)(unsigned short)s) << 16;
  return x.f;
}

// async global->LDS, 16B per lane. LDS dest = wave-uniform base + lane*16.
__device__ __forceinline__ void gld_lds16(const void* g, void* l) {
  __builtin_amdgcn_global_load_lds(
      (const __attribute__((address_space(1))) unsigned int*)g,
      (__attribute__((address_space(3))) unsigned int*)l, 16, 0, 0);
}

// ---------------------------------------------------------------------------
// W_val [256 k][256 n] fp32 -> Wt [256 n][256 k] bf16
// ---------------------------------------------------------------------------
__global__ void convert_wt(const float* __restrict__ W, short* __restrict__ Wt) {
  const int n = blockIdx.x;
  const int k = threadIdx.x;
  Wt[n * 256 + k] = f2bf(W[k * 256 + n]);
}

// ---------------------------------------------------------------------------
// Value projection, m97-style MFMA GEMM with global_load_lds staging.
// Vp = bf16(value @ W_val + b_val), output layout [b][h][pos][32].
// BM=64 (425408=64*6647), BN=128, BK=32, 256 thr = 4 waves (2m x 2n).
// A staged fp32 (cvt to bf16 at frag read); B staged bf16.
// LDS: (8KB A + 8KB B) x 2 dbuf = 32 KB -> ~5 blocks/CU.
// Swizzle (rule #21 both-sides): 16B-granule XOR applied at the per-lane
// GLOBAL source (stays within each row's slice -> coalescing preserved)
// and at the ds_read address. A: g^(row&7). B: g^((n>>1)&3).
// One __syncthreads per K-step (compiler adds vmcnt/lgkm drain).
// ---------------------------------------------------------------------------
__global__ __launch_bounds__(256, 4) void gemm_value_mfma(
    const float* __restrict__ A, const short* __restrict__ Wt,
    const float* __restrict__ bias, short* __restrict__ Vp) {
  __shared__ float As[2][64 * 32];    // [buf][row*32 + k], row = 128 B
  __shared__ short Bs[2][128 * 32];   // [buf][n*32 + k],   row = 64 B

  const int tid = threadIdx.x;
  const int lane = tid & 63;
  const int w = tid >> 6;               // wave 0..3
  const int wm = w >> 1, wn = w & 1;    // 2x2 wave grid
  const size_t m0 = (size_t)blockIdx.x * 64;
  const int col0 = blockIdx.y * 128;

  // ---- staging geometry: 8 instrs each for A and B; wave w does j=2w,2w+1.
  // A instr j: rows 8j..8j+7. lane: r = 8j + (l>>3), dest granule gd = l&7,
  //            src granule gs = gd ^ (r&7). 1KB LDS chunk at byte j*1024.
  const int ja0 = 2 * w, ja1 = 2 * w + 1;
  const int rA0 = 8 * ja0 + (lane >> 3);
  const int rA1 = 8 * ja1 + (lane >> 3);
  const int gsA0 = (lane & 7) ^ (rA0 & 7);
  const int gsA1 = (lane & 7) ^ (rA1 & 7);
  const float* aSrc0 = A + (m0 + rA0) * 256 + gsA0 * 4;   // granule = 4 floats
  const float* aSrc1 = A + (m0 + rA1) * 256 + gsA1 * 4;
  // B instr j: rows n = 16j + (l>>2), gd = l&3, gs = gd ^ ((n>>1)&3).
  const int nB0 = 16 * ja0 + (lane >> 2);
  const int nB1 = 16 * ja1 + (lane >> 2);
  const int gsB0 = (lane & 3) ^ ((nB0 >> 1) & 3);
  const int gsB1 = (lane & 3) ^ ((nB1 >> 1) & 3);
  const short* bSrc0 = Wt + (size_t)(col0 + nB0) * 256 + gsB0 * 8;  // granule = 8 shorts
  const short* bSrc1 = Wt + (size_t)(col0 + nB1) * 256 + gsB1 * 8;

  // ---- fragment-read offsets (with the same XOR swizzle) ----
  const int lr = lane & 15;
  const int lkq = lane >> 4;            // k-quarter 0..3; k = lkq*8 .. +7
  const int rowA_0 = wm * 32 + lr;           // mf = 0
  const int rowA_1 = wm * 32 + 16 + lr;      // mf = 1
  // A float-offsets: row*32 + ((lkq*2+t)^(row&7))*4, t = 0,1
  const int aO00 = rowA_0 * 32 + (((lkq * 2 + 0) ^ (rowA_0 & 7)) * 4);
  const int aO01 = rowA_0 * 32 + (((lkq * 2 + 1) ^ (rowA_0 & 7)) * 4);
  const int aO10 = rowA_1 * 32 + (((lkq * 2 + 0) ^ (rowA_1 & 7)) * 4);
  const int aO11 = rowA_1 * 32 + (((lkq * 2 + 1) ^ (rowA_1 & 7)) * 4);
  // B short-offsets per nf: n*32 + (lkq^((n>>1)&3))*8
  int bO[4];
#pragma unroll
  for (int nf = 0; nf < 4; ++nf) {
    const int n = wn * 64 + nf * 16 + lr;
    bO[nf] = n * 32 + ((lkq ^ ((n >> 1) & 3)) * 8);
  }

  f32x4 acc[2][4];
#pragma unroll
  for (int i = 0; i < 2; ++i)
#pragma unroll
    for (int j = 0; j < 4; ++j) acc[i][j] = (f32x4){0.f, 0.f, 0.f, 0.f};

#define STAGE(buf, kt)                                                  \
  do {                                                                  \
    const int k0_ = (kt) * 32;                                          \
    gld_lds16(aSrc0 + k0_, &As[(buf)][ja0 * 256]);                      \
    gld_lds16(aSrc1 + k0_, &As[(buf)][ja1 * 256]);                      \
    gld_lds16(bSrc0 + k0_, &Bs[(buf)][ja0 * 512]);                      \
    gld_lds16(bSrc1 + k0_, &Bs[(buf)][ja1 * 512]);                      \
  } while (0)

  STAGE(0, 0);
  __syncthreads();

  int cur = 0;
#pragma unroll
  for (int kt = 0; kt < 8; ++kt) {
    if (kt < 7) STAGE(cur ^ 1, kt + 1);
    const float* as = &As[cur][0];
    const short* bs = &Bs[cur][0];
    const f32x4 a00 = *(const f32x4*)(as + aO00);
    const f32x4 a01 = *(const f32x4*)(as + aO01);
    const f32x4 a10 = *(const f32x4*)(as + aO10);
    const f32x4 a11 = *(const f32x4*)(as + aO11);
    bf16x8 bfr[4];
#pragma unroll
    for (int nf = 0; nf < 4; ++nf) bfr[nf] = *(const bf16x8*)(bs + bO[nf]);
    bf16x8 af0, af1;
#pragma unroll
    for (int i = 0; i < 4; ++i) {
      af0[i]     = f2bf(a00[i]);
      af0[i + 4] = f2bf(a01[i]);
      af1[i]     = f2bf(a10[i]);
      af1[i + 4] = f2bf(a11[i]);
    }
#pragma unroll
    for (int nf = 0; nf < 4; ++nf)
      acc[0][nf] = __builtin_amdgcn_mfma_f32_16x16x32_bf16(af0, bfr[nf], acc[0][nf], 0, 0, 0);
#pragma unroll
    for (int nf = 0; nf < 4; ++nf)
      acc[1][nf] = __builtin_amdgcn_mfma_f32_16x16x32_bf16(af1, bfr[nf], acc[1][nf], 0, 0, 0);
    __syncthreads();
    cur ^= 1;
  }
#undef STAGE

  // epilogue: D map col=lane&15, row=(lane>>4)*4+r (m89)
  float bv[4];
#pragma unroll
  for (int nf = 0; nf < 4; ++nf) bv[nf] = bias[col0 + wn * 64 + nf * 16 + lr];
  const int lq4 = lkq * 4;
#pragma unroll
  for (int mf = 0; mf < 2; ++mf) {
#pragma unroll
    for (int r = 0; r < 4; ++r) {
      const unsigned m = (unsigned)m0 + wm * 32 + mf * 16 + lq4 + r;
      const unsigned b_ = m / LV_;
      const unsigned pos = m - b_ * LV_;
#pragma unroll
      for (int nf = 0; nf < 4; ++nf) {
        const int n = col0 + wn * 64 + nf * 16 + lr;
        const int h = n >> 5, c = n & 31;
        Vp[((size_t)(b_ * HEADS_ + h) * LV_ + pos) * HEAD_DIM_ + c] =
            f2bf(acc[mf][nf][r] + bv[nf]);
      }
    }
  }
}

// ---------------------------------------------------------------------------
// Generic fp32 tiled GEMM (small query-side projections).
// ---------------------------------------------------------------------------
__global__ __launch_bounds__(256) void gemm_bias(
    const float* __restrict__ A, const float* __restrict__ B,
    const float* __restrict__ bias, float* __restrict__ C,
    int M, int N, int K) {
  __shared__ float As[16][64 + 1];
  __shared__ float Bs[16][64];

  const int tid = threadIdx.x;
  const int tx = tid & 15;
  const int ty = tid >> 4;
  const int row0 = blockIdx.x * 64;
  const int col0 = blockIdx.y * 64;

  float acc[4][4];
#pragma unroll
  for (int i = 0; i < 4; ++i)
#pragma unroll
    for (int j = 0; j < 4; ++j) acc[i][j] = 0.f;

  for (int k0 = 0; k0 < K; k0 += 16) {
    {
      const int r = tid >> 4;
      const int c = tid & 15;
#pragma unroll
      for (int i = 0; i < 4; ++i)
        As[c][r + i * 16] = A[(size_t)(row0 + r + i * 16) * K + k0 + c];
    }
    {
      const int r = tid >> 6;
      const int c = tid & 63;
#pragma unroll
      for (int i = 0; i < 4; ++i)
        Bs[r + i * 4][c] = B[(size_t)(k0 + r + i * 4) * N + col0 + c];
    }
    __syncthreads();
#pragma unroll
    for (int k = 0; k < 16; ++k) {
      float a[4], b[4];
#pragma unroll
      for (int i = 0; i < 4; ++i) a[i] = As[k][ty + i * 16];
#pragma unroll
      for (int j = 0; j < 4; ++j) b[j] = Bs[k][tx + j * 16];
#pragma unroll
      for (int i = 0; i < 4; ++i)
#pragma unroll
        for (int j = 0; j < 4; ++j) acc[i][j] += a[i] * b[j];
    }
    __syncthreads();
  }

#pragma unroll
  for (int i = 0; i < 4; ++i) {
    const int m = row0 + ty + i * 16;
#pragma unroll
    for (int j = 0; j < 4; ++j) {
      const int n = col0 + tx + j * 16;
      C[(size_t)m * N + n] = acc[i][j] + bias[n];
    }
  }
}

// ---------------------------------------------------------------------------
__global__ void softmax16(const float* __restrict__ logits,
                          float* __restrict__ attn, int ngroups) {
  const int g = blockIdx.x * blockDim.x + threadIdx.x;
  if (g >= ngroups) return;
  const float* in = logits + (size_t)g * 16;
  float v[16];
  float m = -1e30f;
#pragma unroll
  for (int i = 0; i < 16; ++i) { v[i] = in[i]; m = fmaxf(m, v[i]); }
  float s = 0.f;
#pragma unroll
  for (int i = 0; i < 16; ++i) { v[i] = __expf(v[i] - m); s += v[i]; }
  const float inv = 1.0f / s;
  float* out = attn + (size_t)g * 16;
#pragma unroll
  for (int i = 0; i < 16; ++i) out[i] = v[i] * inv;
}

// ---------------------------------------------------------------------------
// Deformable sampling: one thread per (b, q, head, 8-channel group).
// ---------------------------------------------------------------------------
__global__ __launch_bounds__(256) void msda_sample(
    const float* __restrict__ ref_pts,   // [BS*LQ, 4, 2]
    const float* __restrict__ offsets,   // [BS*LQ, 256]  (h,l,p,2)
    const float* __restrict__ attn,      // [BS*LQ, 128]  (h,l,p)
    const short* __restrict__ value_p,   // [b,h,pos,32] bf16
    float* __restrict__ tmp)             // [BS*LQ, 256]
{
  const int t = blockIdx.x * 256 + threadIdx.x;
  const int c8 = t & 3;
  const int h = (t >> 2) & 7;
  const int row = t >> 5;
  const int b = row / LQ_;

  const int HS[4] = {100, 50, 25, 13};
  const int START[4] = {0, 10000, 12500, 13125};

  const float* offr = offsets + (size_t)row * 256 + h * 32;
  const float* attr = attn + (size_t)row * 128 + h * 16;
  const float* refr = ref_pts + (size_t)row * 8;

  float acc[8];
#pragma unroll
  for (int j = 0; j < 8; ++j) acc[j] = 0.f;

#pragma unroll
  for (int l = 0; l < 4; ++l) {
    const int HH = HS[l];
    const int WW = HS[l];
    const float fH = (float)HH, fW = (float)WW;
    const float rx = refr[l * 2 + 0];
    const float ry = refr[l * 2 + 1];
    const short* vbase =
        value_p + ((size_t)(b * HEADS_ + h) * LV_ + START[l]) * HEAD_DIM_ + c8 * 8;
#pragma unroll
    for (int p = 0; p < 4; ++p) {
      const float ox = offr[(l * 4 + p) * 2 + 0];
      const float oy = offr[(l * 4 + p) * 2 + 1];
      const float x = (rx + ox / fW) * fW - 0.5f;
      const float y = (ry + oy / fH) * fH - 0.5f;
      const float x0f = floorf(x), y0f = floorf(y);
      const float fx = x - x0f, fy = y - y0f;
      const int x0 = (int)x0f, y0 = (int)y0f;
      const float wgt = attr[l * 4 + p];
      const float iy0 = (y0 >= 0 && y0 < HH) ? 1.f : 0.f;
      const float iy1 = (y0 + 1 >= 0 && y0 + 1 < HH) ? 1.f : 0.f;
      const float ix0 = (x0 >= 0 && x0 < WW) ? 1.f : 0.f;
      const float ix1 = (x0 + 1 >= 0 && x0 + 1 < WW) ? 1.f : 0.f;
      const float w00 = (1.f - fy) * (1.f - fx) * wgt * iy0 * ix0;
      const float w01 = (1.f - fy) * fx * wgt * iy0 * ix1;
      const float w10 = fy * (1.f - fx) * wgt * iy1 * ix0;
      const float w11 = fy * fx * wgt * iy1 * ix1;
      const int xc0 = min(max(x0, 0), WW - 1);
      const int xc1 = min(max(x0 + 1, 0), WW - 1);
      const int yc0 = min(max(y0, 0), HH - 1);
      const int yc1 = min(max(y0 + 1, 0), HH - 1);
      const bf16x8 q00 = *(const bf16x8*)(vbase + (size_t)(yc0 * WW + xc0) * HEAD_DIM_);
      const bf16x8 q01 = *(const bf16x8*)(vbase + (size_t)(yc0 * WW + xc1) * HEAD_DIM_);
      const bf16x8 q10 = *(const bf16x8*)(vbase + (size_t)(yc1 * WW + xc0) * HEAD_DIM_);
      const bf16x8 q11 = *(const bf16x8*)(vbase + (size_t)(yc1 * WW + xc1) * HEAD_DIM_);
#pragma unroll
      for (int j = 0; j < 8; ++j) {
        acc[j] += w00 * bf2f(q00[j]) + w01 * bf2f(q01[j]) +
                  w10 * bf2f(q10[j]) + w11 * bf2f(q11[j]);
      }
    }
  }
  float* o = tmp + (size_t)row * 256 + h * 32 + c8 * 8;
  f32x4 o0 = {acc[0], acc[1], acc[2], acc[3]};
  f32x4 o1 = {acc[4], acc[5], acc[6], acc[7]};
  *(f32x4*)(o) = o0;
  *(f32x4*)(o + 4) = o1;
}

// ---------------------------------------------------------------------------
extern "C" void kernel_launch(void* const* d_in, const int* in_sizes, int n_in,
                              void* d_out, int out_size, void* d_ws, size_t ws_size,
                              hipStream_t stream) {
  const float* query  = (const float*)d_in[0];
  const float* refpts = (const float*)d_in[1];
  const float* value  = (const float*)d_in[2];
  const float* W_off  = (const float*)d_in[4];
  const float* b_off  = (const float*)d_in[5];
  const float* W_attn = (const float*)d_in[6];
  const float* b_attn = (const float*)d_in[7];
  const float* W_val  = (const float*)d_in[8];
  const float* b_val  = (const float*)d_in[9];
  const float* W_out  = (const float*)d_in[10];
  const float* b_out  = (const float*)d_in[11];
  float* out = (float*)d_out;

  char* ws = (char*)d_ws;
  short* value_p = (short*)ws;                                 // 217,710,592 B
  size_t off = (size_t)BS_ * HEADS_ * LV_ * HEAD_DIM_ * 2;
  float* offsets = (float*)(ws + off); off += (size_t)BS_ * LQ_ * 256 * 4;
  float* logits  = (float*)(ws + off); off += (size_t)BS_ * LQ_ * 128 * 4;
  float* attn    = (float*)(ws + off); off += (size_t)BS_ * LQ_ * 128 * 4;
  float* tmp     = (float*)(ws + off); off += (size_t)BS_ * LQ_ * 256 * 4;
  // Wt (131072 B) aliases tmp: consumed by gemm_value_mfma before msda writes tmp.
  short* Wt = (short*)tmp;

  const int M1 = BS_ * LV_;   // 425408 = 64*6647
  const int MQ = BS_ * LQ_;   // 9600

  convert_wt<<<256, 256, 0, stream>>>(W_val, Wt);
  gemm_value_mfma<<<dim3(M1 / 64, 2), 256, 0, stream>>>(value, Wt, b_val, value_p);
  gemm_bias<<<dim3(MQ / 64, 256 / 64), 256, 0, stream>>>(query, W_off, b_off, offsets, MQ, 256, 256);
  gemm_bias<<<dim3(MQ / 64, 128 / 64), 256, 0, stream>>>(query, W_attn, b_attn, logits, MQ, 128, 256);
  softmax16<<<(MQ * HEADS_ + 255) / 256, 256, 0, stream>>>(logits, attn, MQ * HEADS_);
  msda_sample<<<(MQ * 32) / 256, 256, 0, stream>>>(refpts, offsets, attn, value_p, tmp);
  gemm_bias<<<dim3(MQ / 64, 256 / 64), 256, 0, stream>>>(tmp, W_out, b_out, out, MQ, 256, 256);
}

// Round 5
// 356.977 us; speedup vs baseline: 3.7779x; 1.1215x over previous
//
#include <hip/hip_runtime.h>
#include <hip/hip_bf16.h>

// Problem constants
#define BS_   32
#define LQ_   300
#define LV_   13294
#define EMBED_ 256
#define HEADS_ 8
#define HEAD_DIM_ 32

typedef __attribute__((ext_vector_type(8))) short bf16x8;
typedef __attribute__((ext_vector_type(4))) float f32x4;

__device__ inline short f2bf(float f) {   // RNE fp32->bf16 (bit trick)
  union { float f; unsigned u; } x; x.f = f;
  return (short)((x.u + 0x7FFF + ((x.u >> 16) & 1)) >> 16);
}
__device__ inline float bf2f(short s) {
  union { unsigned u; float f; } x; x.u = ((unsigned)(unsigned short)s) << 16;
  return x.f;
}

// async global->LDS, 16B per lane. LDS dest = wave-uniform base + lane*16.
__device__ __forceinline__ void gld_lds16(const void* g, void* l) {
  __builtin_amdgcn_global_load_lds(
      (const __attribute__((address_space(1))) unsigned int*)g,
      (__attribute__((address_space(3))) unsigned int*)l, 16, 0, 0);
}

// ---------------------------------------------------------------------------
// W [256 k][N n] fp32 -> Wt [N n][256 k] bf16
// ---------------------------------------------------------------------------
__global__ void convert_wt(const float* __restrict__ W, short* __restrict__ Wt,
                           int N) {
  const int n = blockIdx.x;
  const int k = threadIdx.x;
  Wt[n * 256 + k] = f2bf(W[k * N + n]);
}

// ---------------------------------------------------------------------------
// MFMA GEMM with counted-vmcnt 4-buffer pipeline (T3+T4).
// C = A[M,256] @ Wt^T (+bias). BM=64, BN=128, BK=32, 256 thr = 4 waves (2x2).
// A staged fp32 via global_load_lds (cvt->bf16 at frag read); B staged bf16.
// LDS = 4 x (8KB A + 8KB B) = 64 KB -> 2 blocks/CU.
// Pipeline: 3 stages in flight; s_waitcnt vmcnt(8) per step (never 0 in loop).
// STAGE issued AFTER the barrier (WAR-safe: that buffer's readers finished
// before arriving at the barrier; RAW-safe: own-vmcnt + barrier).
// Swizzle (both-sides, rule #21): 16B-granule XOR at per-lane GLOBAL source
// and at ds_read addr. A: g^(row&7). B: g^((n>>1)&3).
// STORE_MODE 0: f32 row-major C (ldc). 1: bf16 Vp layout [b][h][pos][32].
// ---------------------------------------------------------------------------
template <int STORE_MODE>
__global__ __launch_bounds__(256, 2) void gemm_mfma(
    const float* __restrict__ A, const short* __restrict__ Wt,
    const float* __restrict__ bias, void* __restrict__ Cout, int ldc) {
  __shared__ float As[4][64 * 32];    // 4 x 8 KB
  __shared__ short Bs[4][128 * 32];   // 4 x 8 KB

  const int tid = threadIdx.x;
  const int lane = tid & 63;
  const int w = tid >> 6;               // wave 0..3
  const int wm = w >> 1, wn = w & 1;    // 2x2 wave grid
  const size_t m0 = (size_t)blockIdx.x * 64;
  const int col0 = blockIdx.y * 128;

  // staging geometry: 8 lds-load instrs each for A and B; wave w does j=2w,2w+1
  const int ja0 = 2 * w, ja1 = 2 * w + 1;
  const int rA0 = 8 * ja0 + (lane >> 3);
  const int rA1 = 8 * ja1 + (lane >> 3);
  const int gsA0 = (lane & 7) ^ (rA0 & 7);
  const int gsA1 = (lane & 7) ^ (rA1 & 7);
  const float* aSrc0 = A + (m0 + rA0) * 256 + gsA0 * 4;   // granule = 4 floats
  const float* aSrc1 = A + (m0 + rA1) * 256 + gsA1 * 4;
  const int nB0 = 16 * ja0 + (lane >> 2);
  const int nB1 = 16 * ja1 + (lane >> 2);
  const int gsB0 = (lane & 3) ^ ((nB0 >> 1) & 3);
  const int gsB1 = (lane & 3) ^ ((nB1 >> 1) & 3);
  const short* bSrc0 = Wt + (size_t)(col0 + nB0) * 256 + gsB0 * 8;  // granule = 8 shorts
  const short* bSrc1 = Wt + (size_t)(col0 + nB1) * 256 + gsB1 * 8;

  // fragment-read offsets (with the same XOR swizzle)
  const int lr = lane & 15;
  const int lkq = lane >> 4;
  const int rowA_0 = wm * 32 + lr;
  const int rowA_1 = wm * 32 + 16 + lr;
  const int aO00 = rowA_0 * 32 + (((lkq * 2 + 0) ^ (rowA_0 & 7)) * 4);
  const int aO01 = rowA_0 * 32 + (((lkq * 2 + 1) ^ (rowA_0 & 7)) * 4);
  const int aO10 = rowA_1 * 32 + (((lkq * 2 + 0) ^ (rowA_1 & 7)) * 4);
  const int aO11 = rowA_1 * 32 + (((lkq * 2 + 1) ^ (rowA_1 & 7)) * 4);
  int bO[4];
#pragma unroll
  for (int nf = 0; nf < 4; ++nf) {
    const int n = wn * 64 + nf * 16 + lr;
    bO[nf] = n * 32 + ((lkq ^ ((n >> 1) & 3)) * 8);
  }

  f32x4 acc[2][4];
#pragma unroll
  for (int i = 0; i < 2; ++i)
#pragma unroll
    for (int j = 0; j < 4; ++j) acc[i][j] = (f32x4){0.f, 0.f, 0.f, 0.f};

  auto stage = [&](int buf, int kt) {
    const int k0_ = kt * 32;
    gld_lds16(aSrc0 + k0_, &As[buf][ja0 * 256]);
    gld_lds16(aSrc1 + k0_, &As[buf][ja1 * 256]);
    gld_lds16(bSrc0 + k0_, &Bs[buf][ja0 * 512]);
    gld_lds16(bSrc1 + k0_, &Bs[buf][ja1 * 512]);
  };
  auto compute = [&](int buf) {
    const float* as = &As[buf][0];
    const short* bs = &Bs[buf][0];
    const f32x4 a00 = *(const f32x4*)(as + aO00);
    const f32x4 a01 = *(const f32x4*)(as + aO01);
    const f32x4 a10 = *(const f32x4*)(as + aO10);
    const f32x4 a11 = *(const f32x4*)(as + aO11);
    bf16x8 bfr[4];
#pragma unroll
    for (int nf = 0; nf < 4; ++nf) bfr[nf] = *(const bf16x8*)(bs + bO[nf]);
    bf16x8 af0, af1;
#pragma unroll
    for (int i = 0; i < 4; ++i) {
      af0[i]     = f2bf(a00[i]);
      af0[i + 4] = f2bf(a01[i]);
      af1[i]     = f2bf(a10[i]);
      af1[i + 4] = f2bf(a11[i]);
    }
#pragma unroll
    for (int nf = 0; nf < 4; ++nf)
      acc[0][nf] = __builtin_amdgcn_mfma_f32_16x16x32_bf16(af0, bfr[nf], acc[0][nf], 0, 0, 0);
#pragma unroll
    for (int nf = 0; nf < 4; ++nf)
      acc[1][nf] = __builtin_amdgcn_mfma_f32_16x16x32_bf16(af1, bfr[nf], acc[1][nf], 0, 0, 0);
  };

  // prologue: 3 stages in flight (12 VMEM ops/wave)
  stage(0, 0);
  stage(1, 1);
  stage(2, 2);

#define KSTEP(kt, VM)                                        \
  do {                                                       \
    asm volatile("s_waitcnt vmcnt(" #VM ")" ::: "memory");   \
    asm volatile("s_barrier" ::: "memory");                  \
    if ((kt) + 3 < 8) stage(((kt) + 3) & 3, (kt) + 3);       \
    compute((kt) & 3);                                       \
  } while (0)

  KSTEP(0, 8);
  KSTEP(1, 8);
  KSTEP(2, 8);
  KSTEP(3, 8);
  KSTEP(4, 8);
  KSTEP(5, 8);
  KSTEP(6, 4);
  KSTEP(7, 0);
#undef KSTEP

  // epilogue: D map col=lane&15, row=(lane>>4)*4+r (m89)
  float bv[4];
#pragma unroll
  for (int nf = 0; nf < 4; ++nf) bv[nf] = bias[col0 + wn * 64 + nf * 16 + lr];
  const int lq4 = lkq * 4;
#pragma unroll
  for (int mf = 0; mf < 2; ++mf) {
#pragma unroll
    for (int r = 0; r < 4; ++r) {
      const unsigned m = (unsigned)m0 + wm * 32 + mf * 16 + lq4 + r;
#pragma unroll
      for (int nf = 0; nf < 4; ++nf) {
        const int n = col0 + wn * 64 + nf * 16 + lr;
        const float v = acc[mf][nf][r] + bv[nf];
        if (STORE_MODE == 0) {
          ((float*)Cout)[(size_t)m * ldc + n] = v;
        } else {
          const unsigned b_ = m / LV_;
          const unsigned pos = m - b_ * LV_;
          const int h = n >> 5, c = n & 31;
          ((short*)Cout)[((size_t)(b_ * HEADS_ + h) * LV_ + pos) * HEAD_DIM_ + c] = f2bf(v);
        }
      }
    }
  }
}

// ---------------------------------------------------------------------------
__global__ void softmax16(const float* __restrict__ logits,
                          float* __restrict__ attn, int ngroups) {
  const int g = blockIdx.x * blockDim.x + threadIdx.x;
  if (g >= ngroups) return;
  const float* in = logits + (size_t)g * 16;
  float v[16];
  float m = -1e30f;
#pragma unroll
  for (int i = 0; i < 16; ++i) { v[i] = in[i]; m = fmaxf(m, v[i]); }
  float s = 0.f;
#pragma unroll
  for (int i = 0; i < 16; ++i) { v[i] = __expf(v[i] - m); s += v[i]; }
  const float inv = 1.0f / s;
  float* out = attn + (size_t)g * 16;
#pragma unroll
  for (int i = 0; i < 16; ++i) out[i] = v[i] * inv;
}

// ---------------------------------------------------------------------------
// Deformable sampling: one thread per (b, q, head, 8-channel group).
// ---------------------------------------------------------------------------
__global__ __launch_bounds__(256) void msda_sample(
    const float* __restrict__ ref_pts,   // [BS*LQ, 4, 2]
    const float* __restrict__ offsets,   // [BS*LQ, 256]  (h,l,p,2)
    const float* __restrict__ attn,      // [BS*LQ, 128]  (h,l,p)
    const short* __restrict__ value_p,   // [b,h,pos,32] bf16
    float* __restrict__ tmp)             // [BS*LQ, 256]
{
  const int t = blockIdx.x * 256 + threadIdx.x;
  const int c8 = t & 3;
  const int h = (t >> 2) & 7;
  const int row = t >> 5;
  const int b = row / LQ_;

  const int HS[4] = {100, 50, 25, 13};
  const int START[4] = {0, 10000, 12500, 13125};

  const float* offr = offsets + (size_t)row * 256 + h * 32;
  const float* attr = attn + (size_t)row * 128 + h * 16;
  const float* refr = ref_pts + (size_t)row * 8;

  float acc[8];
#pragma unroll
  for (int j = 0; j < 8; ++j) acc[j] = 0.f;

#pragma unroll
  for (int l = 0; l < 4; ++l) {
    const int HH = HS[l];
    const int WW = HS[l];
    const float fH = (float)HH, fW = (float)WW;
    const float rx = refr[l * 2 + 0];
    const float ry = refr[l * 2 + 1];
    const short* vbase =
        value_p + ((size_t)(b * HEADS_ + h) * LV_ + START[l]) * HEAD_DIM_ + c8 * 8;
#pragma unroll
    for (int p = 0; p < 4; ++p) {
      const float ox = offr[(l * 4 + p) * 2 + 0];
      const float oy = offr[(l * 4 + p) * 2 + 1];
      const float x = (rx + ox / fW) * fW - 0.5f;
      const float y = (ry + oy / fH) * fH - 0.5f;
      const float x0f = floorf(x), y0f = floorf(y);
      const float fx = x - x0f, fy = y - y0f;
      const int x0 = (int)x0f, y0 = (int)y0f;
      const float wgt = attr[l * 4 + p];
      const float iy0 = (y0 >= 0 && y0 < HH) ? 1.f : 0.f;
      const float iy1 = (y0 + 1 >= 0 && y0 + 1 < HH) ? 1.f : 0.f;
      const float ix0 = (x0 >= 0 && x0 < WW) ? 1.f : 0.f;
      const float ix1 = (x0 + 1 >= 0 && x0 + 1 < WW) ? 1.f : 0.f;
      const float w00 = (1.f - fy) * (1.f - fx) * wgt * iy0 * ix0;
      const float w01 = (1.f - fy) * fx * wgt * iy0 * ix1;
      const float w10 = fy * (1.f - fx) * wgt * iy1 * ix0;
      const float w11 = fy * fx * wgt * iy1 * ix1;
      const int xc0 = min(max(x0, 0), WW - 1);
      const int xc1 = min(max(x0 + 1, 0), WW - 1);
      const int yc0 = min(max(y0, 0), HH - 1);
      const int yc1 = min(max(y0 + 1, 0), HH - 1);
      const bf16x8 q00 = *(const bf16x8*)(vbase + (size_t)(yc0 * WW + xc0) * HEAD_DIM_);
      const bf16x8 q01 = *(const bf16x8*)(vbase + (size_t)(yc0 * WW + xc1) * HEAD_DIM_);
      const bf16x8 q10 = *(const bf16x8*)(vbase + (size_t)(yc1 * WW + xc0) * HEAD_DIM_);
      const bf16x8 q11 = *(const bf16x8*)(vbase + (size_t)(yc1 * WW + xc1) * HEAD_DIM_);
#pragma unroll
      for (int j = 0; j < 8; ++j) {
        acc[j] += w00 * bf2f(q00[j]) + w01 * bf2f(q01[j]) +
                  w10 * bf2f(q10[j]) + w11 * bf2f(q11[j]);
      }
    }
  }
  float* o = tmp + (size_t)row * 256 + h * 32 + c8 * 8;
  f32x4 o0 = {acc[0], acc[1], acc[2], acc[3]};
  f32x4 o1 = {acc[4], acc[5], acc[6], acc[7]};
  *(f32x4*)(o) = o0;
  *(f32x4*)(o + 4) = o1;
}

// ---------------------------------------------------------------------------
extern "C" void kernel_launch(void* const* d_in, const int* in_sizes, int n_in,
                              void* d_out, int out_size, void* d_ws, size_t ws_size,
                              hipStream_t stream) {
  const float* query  = (const float*)d_in[0];
  const float* refpts = (const float*)d_in[1];
  const float* value  = (const float*)d_in[2];
  const float* W_off  = (const float*)d_in[4];
  const float* b_off  = (const float*)d_in[5];
  const float* W_attn = (const float*)d_in[6];
  const float* b_attn = (const float*)d_in[7];
  const float* W_val  = (const float*)d_in[8];
  const float* b_val  = (const float*)d_in[9];
  const float* W_out  = (const float*)d_in[10];
  const float* b_out  = (const float*)d_in[11];
  float* out = (float*)d_out;

  char* ws = (char*)d_ws;
  short* value_p = (short*)ws;                                 // 217,710,592 B
  size_t off = (size_t)BS_ * HEADS_ * LV_ * HEAD_DIM_ * 2;
  float* offsets = (float*)(ws + off); off += (size_t)BS_ * LQ_ * 256 * 4;
  float* logits  = (float*)(ws + off); off += (size_t)BS_ * LQ_ * 128 * 4;
  float* attn    = (float*)(ws + off); off += (size_t)BS_ * LQ_ * 128 * 4;
  float* tmp     = (float*)(ws + off); off += (size_t)BS_ * LQ_ * 256 * 4;

  // Wt aliasing plan (sequential stream ordering makes each safe):
  //  WtA (W_off, 128KB) and WtB (W_attn, 64KB) live in value_p[0:192KB):
  //    consumed by query GEMMs BEFORE gemm_mfma<1> overwrites value_p.
  //  WtV (W_val, 128KB) lives in tmp: consumed before msda_sample writes tmp.
  //  WtO (W_out, 128KB) reuses value_p AFTER msda_sample is done with it.
  short* WtA = (short*)value_p;
  short* WtB = (short*)value_p + 256 * 256;
  short* WtV = (short*)tmp;
  short* WtO = (short*)value_p;

  const int M1 = BS_ * LV_;   // 425408 = 64*6647
  const int MQ = BS_ * LQ_;   // 9600   = 64*150

  convert_wt<<<256, 256, 0, stream>>>(W_off, WtA, 256);
  convert_wt<<<128, 256, 0, stream>>>(W_attn, WtB, 128);
  gemm_mfma<0><<<dim3(MQ / 64, 2), 256, 0, stream>>>(query, WtA, b_off, offsets, 256);
  gemm_mfma<0><<<dim3(MQ / 64, 1), 256, 0, stream>>>(query, WtB, b_attn, logits, 128);
  softmax16<<<(MQ * HEADS_ + 255) / 256, 256, 0, stream>>>(logits, attn, MQ * HEADS_);
  convert_wt<<<256, 256, 0, stream>>>(W_val, WtV, 256);
  gemm_mfma<1><<<dim3(M1 / 64, 2), 256, 0, stream>>>(value, WtV, b_val, value_p, 0);
  msda_sample<<<(MQ * 32) / 256, 256, 0, stream>>>(refpts, offsets, attn, value_p, tmp);
  convert_wt<<<256, 256, 0, stream>>>(W_out, WtO, 256);
  gemm_mfma<0><<<dim3(MQ / 64, 2), 256, 0, stream>>>(tmp, WtO, b_out, out, 256);
}

// Round 6
// 277.018 us; speedup vs baseline: 4.8683x; 1.2886x over previous
//
#include <hip/hip_runtime.h>
#include <hip/hip_bf16.h>

// Problem constants
#define BS_   32
#define LQ_   300
#define LV_   13294
#define EMBED_ 256
#define HEADS_ 8
#define HEAD_DIM_ 32

typedef __attribute__((ext_vector_type(8))) short bf16x8;
typedef __attribute__((ext_vector_type(4))) float f32x4;

__device__ inline short f2bf(float f) {   // RNE fp32->bf16 (bit trick)
  union { float f; unsigned u; } x; x.f = f;
  return (short)((x.u + 0x7FFF + ((x.u >> 16) & 1)) >> 16);
}
__device__ inline short f2bf_i(float f) { // via HW cvt (compiler may pack)
  union { __hip_bfloat16 h; short s; } u;
  u.h = __float2bfloat16(f);
  return u.s;
}
__device__ inline float bf2f(short s) {
  union { unsigned u; float f; } x; x.u = ((unsigned)(unsigned short)s) << 16;
  return x.f;
}

// async global->LDS, 16B per lane. LDS dest = wave-uniform base + lane*16.
__device__ __forceinline__ void gld_lds16(const void* g, void* l) {
  __builtin_amdgcn_global_load_lds(
      (const __attribute__((address_space(1))) unsigned int*)g,
      (__attribute__((address_space(3))) unsigned int*)l, 16, 0, 0);
}

// ---------------------------------------------------------------------------
// W [256 k][Nsrc n] fp32 -> Wt [256 n][256 k] bf16, zero-padded cols >= Nsrc.
// ---------------------------------------------------------------------------
__global__ void convert_wt(const float* __restrict__ W, short* __restrict__ Wt,
                           int Nsrc) {
  const int n = blockIdx.x;   // 0..255
  const int k = threadIdx.x;  // 0..255
  Wt[n * 256 + k] = (n < Nsrc) ? f2bf(W[k * Nsrc + n]) : (short)0;
}

// ---------------------------------------------------------------------------
// "Big-A" MFMA GEMM: C[M,256] = A[M,256] @ Wt^T (+bias).
// BM=64, BN=256, 256 thr = 4 waves, each wave owns a 64-col slice (n0=w*64).
// B (wave's 64x256 slice) lives ENTIRELY in registers: bfr[4][8] = 128 VGPR,
// loaded once from the L2-resident 128 KB Wt. A (64x256 fp32 = 64 KB) is
// staged ONCE per block via global_load_lds (16 instrs/wave), ONE barrier,
// then 128 MFMAs with no further sync. 2 blocks/CU (VGPR+LDS) => 128 KB/CU
// of staging in flight => HBM-BW-bound, latency amortized per-block.
// A-LDS swizzle (both-sides, rule #21): 16B-granule XOR with row&7 at the
// per-lane global source and at ds_read => 2-way bank aliasing (free).
// STORE_MODE 0: f32 row-major C (ldc, bias valid < Nbias).
// STORE_MODE 1: bf16 Vp layout [b][h][pos][32], epilogue transposed through
//               LDS (reusing A's space) into 16-B coalesced stores.
// ---------------------------------------------------------------------------
template <int STORE_MODE>
__global__ __launch_bounds__(256, 2) void gemm_bigA(
    const float* __restrict__ A, const short* __restrict__ Wt,
    const float* __restrict__ bias, void* __restrict__ Cout,
    int ldc, int Nbias) {
  __shared__ float As[64 * 256];   // 64 KB; reused by the mode-1 epilogue

  const int tid = threadIdx.x;
  const int lane = tid & 63;
  const int w = tid >> 6;          // wave 0..3
  const int n0 = w * 64;           // wave's column slice
  const size_t m0 = (size_t)blockIdx.x * 64;
  const int lr = lane & 15;        // fragment row/col lane
  const int lkq = lane >> 4;       // k-quarter (0..3)

  // ---- stage A: instr j stages row j (1 KB). src granule = lane^(row&7). ----
#pragma unroll
  for (int i = 0; i < 16; ++i) {
    const int row = w * 16 + i;
    gld_lds16(A + (m0 + row) * 256 + ((lane ^ (row & 7)) * 4), As + row * 256);
  }

  // ---- B slice -> registers (32 x 16B loads, L2-resident) ----
  bf16x8 bfr[4][8];
#pragma unroll
  for (int nf = 0; nf < 4; ++nf) {
    const size_t bbase = (size_t)(n0 + nf * 16 + lr) * 256 + lkq * 8;
#pragma unroll
    for (int kt = 0; kt < 8; ++kt)
      bfr[nf][kt] = *(const bf16x8*)(Wt + bbase + kt * 32);
  }

  f32x4 acc[4][4];
#pragma unroll
  for (int i = 0; i < 4; ++i)
#pragma unroll
    for (int j = 0; j < 4; ++j) acc[i][j] = (f32x4){0.f, 0.f, 0.f, 0.f};

  __syncthreads();   // drains vmcnt(0): A in LDS, B in regs

  // ---- main compute: 8 kt x 4 mf x (2 ds_read + cvt + 4 MFMA) ----
#pragma unroll
  for (int kt = 0; kt < 8; ++kt) {
#pragma unroll
    for (int mf = 0; mf < 4; ++mf) {
      const int row = mf * 16 + lr;
      const int gbase = kt * 8 + lkq * 2;
      const f32x4 a0 = *(const f32x4*)(As + row * 256 + ((gbase    ) ^ (row & 7)) * 4);
      const f32x4 a1 = *(const f32x4*)(As + row * 256 + ((gbase + 1) ^ (row & 7)) * 4);
      bf16x8 af;
#pragma unroll
      for (int i = 0; i < 4; ++i) {
        af[i]     = f2bf_i(a0[i]);
        af[i + 4] = f2bf_i(a1[i]);
      }
#pragma unroll
      for (int nf = 0; nf < 4; ++nf)
        acc[mf][nf] = __builtin_amdgcn_mfma_f32_16x16x32_bf16(af, bfr[nf][kt], acc[mf][nf], 0, 0, 0);
    }
  }

  // ---- epilogue ----
  float bv[4];
#pragma unroll
  for (int nf = 0; nf < 4; ++nf) {
    const int n = n0 + nf * 16 + lr;
    bv[nf] = (n < Nbias) ? bias[n] : 0.f;
  }
  const int lq4 = lkq * 4;

  if (STORE_MODE == 0) {
#pragma unroll
    for (int mf = 0; mf < 4; ++mf)
#pragma unroll
      for (int r = 0; r < 4; ++r) {
        const size_t m = m0 + mf * 16 + lq4 + r;
#pragma unroll
        for (int nf = 0; nf < 4; ++nf) {
          const int n = n0 + nf * 16 + lr;
          ((float*)Cout)[m * ldc + n] = acc[mf][nf][r] + bv[nf];
        }
      }
  } else {
    // transpose through LDS (reuse As), then 16-B coalesced stores.
    short* lds2 = (short*)As;          // stride 264 shorts (528 B): 2-way reads
    __syncthreads();                   // all ds_reads of As complete
#pragma unroll
    for (int mf = 0; mf < 4; ++mf)
#pragma unroll
      for (int r = 0; r < 4; ++r) {
        const int row = mf * 16 + lq4 + r;
#pragma unroll
        for (int nf = 0; nf < 4; ++nf)
          lds2[row * 264 + n0 + nf * 16 + lr] = f2bf(acc[mf][nf][r] + bv[nf]);
      }
    __syncthreads();
    // store instr: fixed h, 16 consecutive pos, full 32 ch = 1 KB contiguous
#pragma unroll
    for (int i = 0; i < 8; ++i) {
      const int u = w * 8 + i;               // 0..31
      const int h = u >> 2;
      const int pl = (u & 3) * 16 + (lane >> 2);   // block-local row
      const int co = (lane & 3) * 8;               // channel octet
      const bf16x8 v = *(const bf16x8*)(lds2 + pl * 264 + h * 32 + co);
      const unsigned m = (unsigned)m0 + pl;
      const unsigned b_ = m / LV_;
      const unsigned pos = m - b_ * LV_;
      *(bf16x8*)((short*)Cout + ((size_t)(b_ * HEADS_ + h) * LV_ + pos) * HEAD_DIM_ + co) = v;
    }
  }
}

// ---------------------------------------------------------------------------
// Softmax over 16 per (row, head); logits row-stride 256 (cols 128+ unused).
// ---------------------------------------------------------------------------
__global__ void softmax16(const float* __restrict__ logits,
                          float* __restrict__ attn, int ngroups) {
  const int g = blockIdx.x * blockDim.x + threadIdx.x;
  if (g >= ngroups) return;
  const int row = g >> 3, h = g & 7;
  const float* in = logits + (size_t)row * 256 + h * 16;
  float v[16];
  float m = -1e30f;
#pragma unroll
  for (int i = 0; i < 16; ++i) { v[i] = in[i]; m = fmaxf(m, v[i]); }
  float s = 0.f;
#pragma unroll
  for (int i = 0; i < 16; ++i) { v[i] = __expf(v[i] - m); s += v[i]; }
  const float inv = 1.0f / s;
  float* out = attn + (size_t)g * 16;
#pragma unroll
  for (int i = 0; i < 16; ++i) out[i] = v[i] * inv;
}

// ---------------------------------------------------------------------------
// Deformable sampling: one thread per (b, q, head, 8-channel group).
// ---------------------------------------------------------------------------
__global__ __launch_bounds__(256) void msda_sample(
    const float* __restrict__ ref_pts,   // [BS*LQ, 4, 2]
    const float* __restrict__ offsets,   // [BS*LQ, 256]  (h,l,p,2)
    const float* __restrict__ attn,      // [BS*LQ, 128]  (h,l,p)
    const short* __restrict__ value_p,   // [b,h,pos,32] bf16
    float* __restrict__ tmp)             // [BS*LQ, 256]
{
  const int t = blockIdx.x * 256 + threadIdx.x;
  const int c8 = t & 3;
  const int h = (t >> 2) & 7;
  const int row = t >> 5;
  const int b = row / LQ_;

  const int HS[4] = {100, 50, 25, 13};
  const int START[4] = {0, 10000, 12500, 13125};

  const float* offr = offsets + (size_t)row * 256 + h * 32;
  const float* attr = attn + (size_t)row * 128 + h * 16;
  const float* refr = ref_pts + (size_t)row * 8;

  float acc[8];
#pragma unroll
  for (int j = 0; j < 8; ++j) acc[j] = 0.f;

#pragma unroll
  for (int l = 0; l < 4; ++l) {
    const int HH = HS[l];
    const int WW = HS[l];
    const float fH = (float)HH, fW = (float)WW;
    const float rx = refr[l * 2 + 0];
    const float ry = refr[l * 2 + 1];
    const short* vbase =
        value_p + ((size_t)(b * HEADS_ + h) * LV_ + START[l]) * HEAD_DIM_ + c8 * 8;
#pragma unroll
    for (int p = 0; p < 4; ++p) {
      const float ox = offr[(l * 4 + p) * 2 + 0];
      const float oy = offr[(l * 4 + p) * 2 + 1];
      const float x = (rx + ox / fW) * fW - 0.5f;
      const float y = (ry + oy / fH) * fH - 0.5f;
      const float x0f = floorf(x), y0f = floorf(y);
      const float fx = x - x0f, fy = y - y0f;
      const int x0 = (int)x0f, y0 = (int)y0f;
      const float wgt = attr[l * 4 + p];
      const float iy0 = (y0 >= 0 && y0 < HH) ? 1.f : 0.f;
      const float iy1 = (y0 + 1 >= 0 && y0 + 1 < HH) ? 1.f : 0.f;
      const float ix0 = (x0 >= 0 && x0 < WW) ? 1.f : 0.f;
      const float ix1 = (x0 + 1 >= 0 && x0 + 1 < WW) ? 1.f : 0.f;
      const float w00 = (1.f - fy) * (1.f - fx) * wgt * iy0 * ix0;
      const float w01 = (1.f - fy) * fx * wgt * iy0 * ix1;
      const float w10 = fy * (1.f - fx) * wgt * iy1 * ix0;
      const float w11 = fy * fx * wgt * iy1 * ix1;
      const int xc0 = min(max(x0, 0), WW - 1);
      const int xc1 = min(max(x0 + 1, 0), WW - 1);
      const int yc0 = min(max(y0, 0), HH - 1);
      const int yc1 = min(max(y0 + 1, 0), HH - 1);
      const bf16x8 q00 = *(const bf16x8*)(vbase + (size_t)(yc0 * WW + xc0) * HEAD_DIM_);
      const bf16x8 q01 = *(const bf16x8*)(vbase + (size_t)(yc0 * WW + xc1) * HEAD_DIM_);
      const bf16x8 q10 = *(const bf16x8*)(vbase + (size_t)(yc1 * WW + xc0) * HEAD_DIM_);
      const bf16x8 q11 = *(const bf16x8*)(vbase + (size_t)(yc1 * WW + xc1) * HEAD_DIM_);
#pragma unroll
      for (int j = 0; j < 8; ++j) {
        acc[j] += w00 * bf2f(q00[j]) + w01 * bf2f(q01[j]) +
                  w10 * bf2f(q10[j]) + w11 * bf2f(q11[j]);
      }
    }
  }
  float* o = tmp + (size_t)row * 256 + h * 32 + c8 * 8;
  f32x4 o0 = {acc[0], acc[1], acc[2], acc[3]};
  f32x4 o1 = {acc[4], acc[5], acc[6], acc[7]};
  *(f32x4*)(o) = o0;
  *(f32x4*)(o + 4) = o1;
}

// ---------------------------------------------------------------------------
extern "C" void kernel_launch(void* const* d_in, const int* in_sizes, int n_in,
                              void* d_out, int out_size, void* d_ws, size_t ws_size,
                              hipStream_t stream) {
  const float* query  = (const float*)d_in[0];
  const float* refpts = (const float*)d_in[1];
  const float* value  = (const float*)d_in[2];
  const float* W_off  = (const float*)d_in[4];
  const float* b_off  = (const float*)d_in[5];
  const float* W_attn = (const float*)d_in[6];
  const float* b_attn = (const float*)d_in[7];
  const float* W_val  = (const float*)d_in[8];
  const float* b_val  = (const float*)d_in[9];
  const float* W_out  = (const float*)d_in[10];
  const float* b_out  = (const float*)d_in[11];
  float* out = (float*)d_out;

  char* ws = (char*)d_ws;
  short* value_p = (short*)ws;                                 // 217,710,592 B
  size_t off = (size_t)BS_ * HEADS_ * LV_ * HEAD_DIM_ * 2;
  float* offsets = (float*)(ws + off); off += (size_t)BS_ * LQ_ * 256 * 4;
  float* attn    = (float*)(ws + off); off += (size_t)BS_ * LQ_ * 128 * 4;
  float* tmp     = (float*)(ws + off); off += (size_t)BS_ * LQ_ * 256 * 4;

  // Aliasing plan (sequential stream ordering makes each safe):
  //  WtA/WtB in value_p[0:256KB): consumed by query GEMMs (steps 3-4)
  //    BEFORE step 7 overwrites value_p.
  //  logits = tmp (9.83 MB): written step 4, consumed by softmax step 5.
  //  WtV = tmp[0:128KB): written step 6 (logits dead), consumed step 7,
  //    overwritten by sampler output step 8.
  //  WtO = value_p[0:128KB): written step 9 AFTER sampler read value_p.
  short* WtA = (short*)value_p;
  short* WtB = (short*)value_p + 256 * 256;
  float* logits = tmp;
  short* WtV = (short*)tmp;
  short* WtO = (short*)value_p;

  const int M1 = BS_ * LV_;   // 425408 = 64*6647
  const int MQ = BS_ * LQ_;   // 9600   = 64*150

  convert_wt<<<256, 256, 0, stream>>>(W_off, WtA, 256);
  convert_wt<<<256, 256, 0, stream>>>(W_attn, WtB, 128);
  gemm_bigA<0><<<MQ / 64, 256, 0, stream>>>(query, WtA, b_off, offsets, 256, 256);
  gemm_bigA<0><<<MQ / 64, 256, 0, stream>>>(query, WtB, b_attn, logits, 256, 128);
  softmax16<<<(MQ * HEADS_ + 255) / 256, 256, 0, stream>>>(logits, attn, MQ * HEADS_);
  convert_wt<<<256, 256, 0, stream>>>(W_val, WtV, 256);
  gemm_bigA<1><<<M1 / 64, 256, 0, stream>>>(value, WtV, b_val, value_p, 0, 256);
  msda_sample<<<(MQ * 32) / 256, 256, 0, stream>>>(refpts, offsets, attn, value_p, tmp);
  convert_wt<<<256, 256, 0, stream>>>(W_out, WtO, 256);
  gemm_bigA<0><<<MQ / 64, 256, 0, stream>>>(tmp, WtO, b_out, out, 256, 256);
}